// Round 5
// baseline (398.830 us; speedup 1.0000x reference)
//
#include <hip/hip_runtime.h>

typedef __bf16 bf16;
typedef __bf16 bf16x8 __attribute__((ext_vector_type(8)));
typedef __bf16 bf16x4 __attribute__((ext_vector_type(4)));
typedef float f32x4 __attribute__((ext_vector_type(4)));

#define MFMA16(a, b, c) __builtin_amdgcn_mfma_f32_16x16x32_bf16(a, b, c, 0, 0, 0)

// async global -> LDS, 16 B per lane. lds ptr must be WAVE-UNIFORM base;
// HW places lane i at base + i*16.
#define GLL(lds, g)                                                    \
  __builtin_amdgcn_global_load_lds(                                    \
      (const __attribute__((address_space(1))) void*)(g),              \
      (__attribute__((address_space(3))) void*)(lds), 16, 0, 0)

// ---------------- fused prologue: cache copy + x cvt + weight transposes ------
// All four are independent; one dispatch lets them co-schedule instead of
// serializing as separate graph nodes.
__global__ __launch_bounds__(256) void prep_kernel(
    const float* __restrict__ kc, const float* __restrict__ vc,
    float* __restrict__ kout, float* __restrict__ vout,
    const int* __restrict__ p_ci, const float* __restrict__ x,
    bf16* __restrict__ xb, const float* __restrict__ wq,
    const float* __restrict__ wk, const float* __restrict__ wv,
    bf16* __restrict__ wqkv_t, const float* __restrict__ wo,
    bf16* __restrict__ wo_t) {
  const int blk = blockIdx.x;
  const int tid = threadIdx.x;
  if (blk < 8192) {  // ---- cache copy, skipping the overwritten [ci,ci+1024) ----
    const int s = (blk & 1023) * 4 + (tid >> 6);
    const int bk = blk >> 10;
    const int ci = *p_ci;
    if ((unsigned)(s - ci) < 1024u) return;  // wave-uniform
    const long base = ((long)bk * 4096 + s) * 64 + (tid & 63);
    ((float4*)kout)[base] = ((const float4*)kc)[base];
    ((float4*)vout)[base] = ((const float4*)vc)[base];
    return;
  }
  if (blk < 13312) {  // ---- x f32 -> bf16 (float4/thread) ----
    const long i = (long)(blk - 8192) * 256 + tid;
    const float4 v = ((const float4*)x)[i];
    bf16x4 o4;
    o4.x = (bf16)v.x; o4.y = (bf16)v.y; o4.z = (bf16)v.z; o4.w = (bf16)v.w;
    ((bf16x4*)xb)[i] = o4;
    return;
  }
  __shared__ float tile[32][33];
  const int tx = tid & 31, ty = tid >> 5;  // 32 x 8
  if (blk < 23552) {  // ---- [wq|wk|wv] (K x N) -> (N x K) bf16 ----
    const int idx = blk - 13312;            // 80 x 128
    const int k0 = (idx % 80) * 32, n0 = (idx / 80) * 32;
    const float* src; int col, srcN;
    if (n0 < 2048)      { src = wq; col = n0;        srcN = 2048; }
    else if (n0 < 3072) { src = wk; col = n0 - 2048; srcN = 1024; }
    else                { src = wv; col = n0 - 3072; srcN = 1024; }
#pragma unroll
    for (int i = 0; i < 4; ++i)
      tile[ty + i * 8][tx] = src[(long)(k0 + ty + i * 8) * srcN + col + tx];
    __syncthreads();
#pragma unroll
    for (int i = 0; i < 4; ++i)
      wqkv_t[(long)(n0 + ty + i * 8) * 2560 + k0 + tx] = (bf16)tile[tx][ty + i * 8];
    return;
  }
  {  // ---- wo (2048 x 2560) -> (2560 x 2048) bf16 ----
    const int idx = blk - 23552;            // 64 x 80
    const int k0 = (idx & 63) * 32, n0 = (idx >> 6) * 32;
#pragma unroll
    for (int i = 0; i < 4; ++i)
      tile[ty + i * 8][tx] = wo[(long)(k0 + ty + i * 8) * 2560 + n0 + tx];
    __syncthreads();
#pragma unroll
    for (int i = 0; i < 4; ++i)
      wo_t[(long)(n0 + ty + i * 8) * 2048 + k0 + tx] = (bf16)tile[tx][ty + i * 8];
  }
}

// ---------------- transpose new V slice (f32, [s][d]) -> vt bf16 [d][s] ----------------
__global__ __launch_bounds__(256) void v_trans_kernel(const float* __restrict__ vout,
                                                      const int* __restrict__ p_ci,
                                                      bf16* __restrict__ vt) {
  __shared__ float tile[32][33];
  const int s0 = blockIdx.x * 32, d0 = blockIdx.y * 32, bk = blockIdx.z;
  const int ci = *p_ci;
  const int tx = threadIdx.x, ty = threadIdx.y;
  const float* src = vout + ((long)bk * 4096 + ci) * 256;
#pragma unroll
  for (int i = 0; i < 4; ++i)
    tile[ty + i * 8][tx] = src[(long)(s0 + ty + i * 8) * 256 + d0 + tx];
  __syncthreads();
  bf16* dstb = vt + ((long)bk * 256 + d0) * 1024 + s0;
#pragma unroll
  for (int i = 0; i < 4; ++i)
    dstb[(long)(ty + i * 8) * 1024 + tx] = (bf16)tile[tx][ty + i * 8];
}

// ---------------- bf16 MFMA GEMM: C(MxN) = A(MxK) * BT(NxK)^T ----------------
// R5: BK=32, explicit LDS double-buffer; GLL prefetch of tile k+1 issued right
// after the barrier, drains during compute of tile k (one barrier per iter).
// Wave layout 2x2, each wave (BM/2)x(BN/2). Chunk swizzle (R3-verified):
// phys slot = (gchunk + (row>>1)) & 3 -> conflict-free frag ds_read_b128.
template <int BM, int BN, int K, int N, typename OutT>
__global__ __launch_bounds__(256) void gemm_kernel(const bf16* __restrict__ A,
                                                   const bf16* __restrict__ BT,
                                                   OutT* __restrict__ C) {
  __shared__ bf16 As[2 * BM * 32];
  __shared__ bf16 Bs[2 * BN * 32];
  const int bm = blockIdx.x, bn = blockIdx.y;
  const int tid = threadIdx.x;
  const int wave = tid >> 6, lane = tid & 63;
  const int quad = lane >> 4, l16 = lane & 15;
  constexpr int WM = BM / 2, WN = BN / 2;
  constexpr int MI = WM / 16, NI = WN / 16;
  const int wm = (wave & 1) * WM, wn = (wave >> 1) * WN;
  f32x4 acc[MI][NI] = {};
  const int srow = tid >> 2;   // staging row within 64-row group
  const int sslot = tid & 3;
  const bf16* Ag = A + (long)(bm * BM) * K;
  const bf16* Bg = BT + (long)(bn * BN) * K;
  auto stage = [&](int buf, int k0) {
#pragma unroll
    for (int i = 0; i < BM / 64; ++i) {
      const int r = i * 64 + srow;
      const int cc = (sslot - (r >> 1)) & 3;  // global chunk for this phys slot
      GLL(As + buf * BM * 32 + (i * 256 + wave * 64) * 8,
          Ag + (long)r * K + k0 + cc * 8);
    }
#pragma unroll
    for (int i = 0; i < BN / 64; ++i) {
      const int r = i * 64 + srow;
      const int cc = (sslot - (r >> 1)) & 3;
      GLL(Bs + buf * BN * 32 + (i * 256 + wave * 64) * 8,
          Bg + (long)r * K + k0 + cc * 8);
    }
  };
  stage(0, 0);
  int buf = 0;
  for (int k0 = 0; k0 < K; k0 += 32) {
    __syncthreads();  // drains vmcnt: buf ready; prev iter's ds_reads done
    if (k0 + 32 < K) stage(buf ^ 1, k0 + 32);  // prefetch overlaps compute below
    const bf16* Ab = As + buf * BM * 32;
    const bf16* Bb = Bs + buf * BN * 32;
    bf16x8 af[MI], bfr[NI];
#pragma unroll
    for (int mi = 0; mi < MI; ++mi) {
      const int r = wm + mi * 16 + l16;
      af[mi] = *(const bf16x8*)(Ab + r * 32 + (((quad + (r >> 1)) & 3) * 8));
    }
#pragma unroll
    for (int ni = 0; ni < NI; ++ni) {
      const int r = wn + ni * 16 + l16;
      bfr[ni] = *(const bf16x8*)(Bb + r * 32 + (((quad + (r >> 1)) & 3) * 8));
    }
#pragma unroll
    for (int mi = 0; mi < MI; ++mi)
#pragma unroll
      for (int ni = 0; ni < NI; ++ni)
        acc[mi][ni] = MFMA16(af[mi], bfr[ni], acc[mi][ni]);
    buf ^= 1;
  }
  const int crow = bm * BM + wm + quad * 4;
  const int ccol = bn * BN + wn + l16;
#pragma unroll
  for (int mi = 0; mi < MI; ++mi)
#pragma unroll
    for (int ni = 0; ni < NI; ++ni)
#pragma unroll
      for (int r = 0; r < 4; ++r)
        C[(long)(crow + mi * 16 + r) * N + ccol + ni * 16] = (OutT)acc[mi][ni][r];
}

// ---------------- RMSNorm + RoPE + cache scatter (qkv now bf16) ----------------
__global__ __launch_bounds__(256) void normrope_kernel(
    const bf16* __restrict__ qkv, const float* __restrict__ qw,
    const float* __restrict__ kw, const int* __restrict__ p_pos,
    const int* __restrict__ p_ci, float* __restrict__ kout,
    float* __restrict__ vout, bf16* __restrict__ q_bf, bf16* __restrict__ k_bf) {
  const int bt = blockIdx.x, slot = blockIdx.y;
  const int t = bt & 1023, b = bt >> 10;
  const int d = threadIdx.x;
  const float val = (float)qkv[(long)bt * 4096 + slot * 256 + d];
  const int ci = *p_ci;
  if (slot >= 12) {  // v: plain scatter into cache
    vout[((long)(b * 4 + (slot - 12)) * 4096 + ci + t) * 256 + d] = val;
    return;
  }
  __shared__ float red[4];
  __shared__ float rowbuf[256];
  float ss = val * val;
#pragma unroll
  for (int i = 1; i < 64; i <<= 1) ss += __shfl_xor(ss, i);
  if ((d & 63) == 0) red[d >> 6] = ss;
  __syncthreads();
  const float tot = red[0] + red[1] + red[2] + red[3];
  const float rstd = rsqrtf(tot * (1.0f / 256.0f) + 1e-6f);
  const bool isq = slot < 8;
  const float wv = isq ? qw[d] : kw[d];
  const float nv = val * rstd * (1.0f + wv);
  rowbuf[d] = nv;
  __syncthreads();
  const int e = d & 127;
  const float inv_freq = exp2f((float)e * -0.10381025296522976f);
  const float ang = (float)(*p_pos + t) * inv_freq;
  float sn, cs;
  sincosf(ang, &sn, &cs);
  float outv;
  if (d < 128) outv = nv * cs - rowbuf[d + 128] * sn;
  else         outv = nv * cs + rowbuf[d - 128] * sn;
  if (isq) {
    q_bf[((long)(b * 8 + slot) * 1024 + t) * 256 + d] = (bf16)outv;
  } else {
    const int kh = slot - 8;
    kout[((long)(b * 4 + kh) * 4096 + ci + t) * 256 + d] = outv;
    k_bf[((long)(b * 4 + kh) * 1024 + t) * 256 + d] = (bf16)outv;
  }
}

// ---------------- flash attention over the T new tokens (all valid, no mask) ----
__global__ __launch_bounds__(256) void attn_kernel(const bf16* __restrict__ q_bf,
                                                   const bf16* __restrict__ k_bf,
                                                   const bf16* __restrict__ vt_bf,
                                                   bf16* __restrict__ attn) {
  __shared__ bf16 Ks[64 * 256];   // [s][d], chunk-swizzled
  __shared__ bf16 Vs[256 * 64];   // [d][s], chunk-swizzled
  __shared__ bf16 Ps[64 * 72];    // [t][s], +8 pad (VALU-written)
  const int qt = blockIdx.x, h = blockIdx.y, b = blockIdx.z;
  const int kvh = h >> 1;
  const int tid = threadIdx.x;
  const int wave = tid >> 6, lane = tid & 63, quad = lane >> 4, l16 = lane & 15;
  bf16x8 qf[8];
  const bf16* qg =
      q_bf + ((long)(b * 8 + h) * 1024 + qt * 64 + wave * 16 + l16) * 256 + quad * 8;
#pragma unroll
  for (int i = 0; i < 8; ++i) qf[i] = *(const bf16x8*)(qg + i * 32);
  f32x4 o[16] = {};
  float m_r[4] = {-1e30f, -1e30f, -1e30f, -1e30f};
  float l_r[4] = {0.f, 0.f, 0.f, 0.f};
  const float sfac = 0.0625f * 1.44269504088896f;  // SCALE * log2(e)
  const bf16* kgb = k_bf + (long)(b * 4 + kvh) * 1024 * 256;
  const bf16* vgb = vt_bf + (long)(b * 4 + kvh) * 256 * 1024;
  const int krow = tid >> 5, kccp = tid & 31;
  const int kcc = kccp ^ (krow & 7);
  const int vrow0 = tid >> 3, vccp = tid & 7;
  for (int st = 0; st < 16; ++st) {
    __syncthreads();  // previous iter's ds_reads done
#pragma unroll
    for (int i = 0; i < 8; ++i) {  // K tile 64x256: rows krow + i*8
      GLL(Ks + (i * 256 + wave * 64) * 8,
          kgb + (long)(st * 64 + krow + i * 8) * 256 + kcc * 8);
    }
#pragma unroll
    for (int i = 0; i < 8; ++i) {  // V^T tile 256x64: rows vrow0 + i*32
      const int vr = vrow0 + i * 32;
      GLL(Vs + (i * 256 + wave * 64) * 8,
          vgb + (long)vr * 1024 + st * 64 + (vccp ^ (vr & 7)) * 8);
    }
    __syncthreads();  // drains vmcnt -> tiles visible
    f32x4 sacc[4] = {};
#pragma unroll
    for (int kk = 0; kk < 8; ++kk) {
#pragma unroll
      for (int ni = 0; ni < 4; ++ni) {
        const int r = ni * 16 + l16;
        bf16x8 kf = *(const bf16x8*)(Ks + r * 256 + (((kk * 4 + quad) ^ (r & 7)) * 8));
        sacc[ni] = MFMA16(qf[kk], kf, sacc[ni]);
      }
    }
    float alpha_r[4];
#pragma unroll
    for (int r = 0; r < 4; ++r) {
      float s0 = sacc[0][r] * sfac, s1 = sacc[1][r] * sfac;
      float s2 = sacc[2][r] * sfac, s3 = sacc[3][r] * sfac;
      float mx = fmaxf(fmaxf(s0, s1), fmaxf(s2, s3));
#pragma unroll
      for (int dd = 1; dd < 16; dd <<= 1) mx = fmaxf(mx, __shfl_xor(mx, dd));
      float mnew = fmaxf(m_r[r], mx);
      float al = exp2f(m_r[r] - mnew);
      m_r[r] = mnew;
      alpha_r[r] = al;
      float p0 = exp2f(s0 - mnew), p1 = exp2f(s1 - mnew);
      float p2 = exp2f(s2 - mnew), p3 = exp2f(s3 - mnew);
      float rs = p0 + p1 + p2 + p3;
#pragma unroll
      for (int dd = 1; dd < 16; dd <<= 1) rs += __shfl_xor(rs, dd);
      l_r[r] = l_r[r] * al + rs;
      const int prow = (wave * 16 + quad * 4 + r) * 72;
      Ps[prow + l16] = (bf16)p0;
      Ps[prow + 16 + l16] = (bf16)p1;
      Ps[prow + 32 + l16] = (bf16)p2;
      Ps[prow + 48 + l16] = (bf16)p3;
    }
#pragma unroll
    for (int n2 = 0; n2 < 16; ++n2) {
      f32x4 tv = o[n2];
      tv.x *= alpha_r[0]; tv.y *= alpha_r[1]; tv.z *= alpha_r[2]; tv.w *= alpha_r[3];
      o[n2] = tv;
    }
    __syncthreads();  // P visible
    bf16x8 pf0 = *(const bf16x8*)(Ps + (wave * 16 + l16) * 72 + quad * 8);
    bf16x8 pf1 = *(const bf16x8*)(Ps + (wave * 16 + l16) * 72 + 32 + quad * 8);
#pragma unroll
    for (int n2 = 0; n2 < 16; ++n2) {
      const int r = n2 * 16 + l16;
      bf16x8 vf0 = *(const bf16x8*)(Vs + r * 64 + ((quad ^ (r & 7)) * 8));
      o[n2] = MFMA16(pf0, vf0, o[n2]);
      bf16x8 vf1 = *(const bf16x8*)(Vs + r * 64 + (((4 + quad) ^ (r & 7)) * 8));
      o[n2] = MFMA16(pf1, vf1, o[n2]);
    }
  }
  float inv_l[4];
#pragma unroll
  for (int r = 0; r < 4; ++r) inv_l[r] = 1.0f / l_r[r];
  bf16* og = attn + ((long)(b * 1024 + qt * 64 + wave * 16 + quad * 4)) * 2048 +
             h * 256 + l16;
#pragma unroll
  for (int n2 = 0; n2 < 16; ++n2)
#pragma unroll
    for (int r = 0; r < 4; ++r)
      og[(long)r * 2048 + n2 * 16] = (bf16)(o[n2][r] * inv_l[r]);
}

extern "C" void kernel_launch(void* const* d_in, const int* in_sizes, int n_in,
                              void* d_out, int out_size, void* d_ws, size_t ws_size,
                              hipStream_t stream) {
  const float* x = (const float*)d_in[0];
  const float* k_cache = (const float*)d_in[1];
  const float* v_cache = (const float*)d_in[2];
  const float* wq = (const float*)d_in[3];
  const float* wk = (const float*)d_in[4];
  const float* wv = (const float*)d_in[5];
  const float* wo = (const float*)d_in[6];
  const float* qnw = (const float*)d_in[7];
  const float* knw = (const float*)d_in[8];
  const int* p_pos = (const int*)d_in[9];
  const int* p_ci = (const int*)d_in[10];

  float* out0 = (float*)d_out;                    // (2,1024,2560)
  float* kout = out0 + (long)2 * 1024 * 2560;     // (2,4,4096,256)
  float* vout = kout + (long)2 * 4 * 4096 * 256;  // (2,4,4096,256)

  char* w = (char*)d_ws;
  bf16* x_bf = (bf16*)(w);                  // 2048x2560 bf16        10,485,760 B
  bf16* wqkv_t = (bf16*)(w + 10485760);     // 4096x2560 bf16        20,971,520 B
  bf16* wo_t = (bf16*)(w + 31457280);       // 2560x2048 bf16        10,485,760 B
  bf16* qkv = (bf16*)(w + 41943040);        // 2048x4096 bf16        16,777,216 B
  bf16* q_bf = (bf16*)(w + 58720256);       // (2,8,1024,256) bf16    8,388,608 B
  bf16* k_bf = (bf16*)(w + 67108864);       // (2,4,1024,256) bf16    4,194,304 B
  bf16* vt_bf = (bf16*)(w + 71303168);      // (2,4,256,1024) bf16    4,194,304 B
  bf16* attn_b = (bf16*)(w + 75497472);     // 2048x2048 bf16         8,388,608 B

  // 1. fused prologue (cache copy + conversions + transposes), one dispatch
  prep_kernel<<<28672, 256, 0, stream>>>(k_cache, v_cache, kout, vout, p_ci, x,
                                         x_bf, wq, wk, wv, wqkv_t, wo, wo_t);

  // 2. fused QKV projection — 128x128 dbuf tiles, bf16 output
  gemm_kernel<128, 128, 2560, 4096, bf16>
      <<<dim3(16, 32), 256, 0, stream>>>(x_bf, wqkv_t, qkv);

  // 3. rmsnorm + rope + cache scatter
  normrope_kernel<<<dim3(2048, 16), 256, 0, stream>>>(qkv, qnw, knw, p_pos, p_ci,
                                                      kout, vout, q_bf, k_bf);

  // 4. transpose new V slice for PV matmul
  dim3 tb(32, 8);
  v_trans_kernel<<<dim3(32, 8, 8), tb, 0, stream>>>(vout, p_ci, vt_bf);

  // 5. attention
  attn_kernel<<<dim3(16, 8, 2), 256, 0, stream>>>(q_bf, k_bf, vt_bf, attn_b);

  // 6. output projection — 64x128 dbuf tiles (grid 32x20 = 640 blocks), f32 out
  gemm_kernel<64, 128, 2048, 2560, float>
      <<<dim3(32, 20), 256, 0, stream>>>(attn_b, wo_t, out0);
}

// Round 6
// 393.810 us; speedup vs baseline: 1.0127x; 1.0127x over previous
//
#include <hip/hip_runtime.h>

typedef __bf16 bf16;
typedef __bf16 bf16x8 __attribute__((ext_vector_type(8)));
typedef __bf16 bf16x4 __attribute__((ext_vector_type(4)));
typedef float f32x4 __attribute__((ext_vector_type(4)));

#define MFMA16(a, b, c) __builtin_amdgcn_mfma_f32_16x16x32_bf16(a, b, c, 0, 0, 0)

// async global -> LDS, 16 B per lane. lds ptr must be WAVE-UNIFORM base;
// HW places lane i at base + i*16.
#define GLL(lds, g)                                                    \
  __builtin_amdgcn_global_load_lds(                                    \
      (const __attribute__((address_space(1))) void*)(g),              \
      (__attribute__((address_space(3))) void*)(lds), 16, 0, 0)

// ---------------- fused prologue ----------------
// blocks [0,8192): cache copy (skip overwritten slice)
// blocks [8192,13312): x f32->bf16
// blocks [13312,15872): wqkv transpose, 64x64 tiles (40 k-tiles x 64 n-tiles)
// blocks [15872,17152): wo transpose, 64x64 tiles (32 k-tiles x 40 n-tiles)
__global__ __launch_bounds__(256) void prep_kernel(
    const float* __restrict__ kc, const float* __restrict__ vc,
    float* __restrict__ kout, float* __restrict__ vout,
    const int* __restrict__ p_ci, const float* __restrict__ x,
    bf16* __restrict__ xb, const float* __restrict__ wq,
    const float* __restrict__ wk, const float* __restrict__ wv,
    bf16* __restrict__ wqkv_t, const float* __restrict__ wo,
    bf16* __restrict__ wo_t) {
  const int blk = blockIdx.x;
  const int tid = threadIdx.x;
  if (blk < 8192) {  // ---- cache copy ----
    const int s = (blk & 1023) * 4 + (tid >> 6);
    const int bk = blk >> 10;
    const int ci = *p_ci;
    if ((unsigned)(s - ci) < 1024u) return;  // wave-uniform
    const long base = ((long)bk * 4096 + s) * 64 + (tid & 63);
    ((float4*)kout)[base] = ((const float4*)kc)[base];
    ((float4*)vout)[base] = ((const float4*)vc)[base];
    return;
  }
  if (blk < 13312) {  // ---- x f32 -> bf16 ----
    const long i = (long)(blk - 8192) * 256 + tid;
    const float4 v = ((const float4*)x)[i];
    bf16x4 o4;
    o4.x = (bf16)v.x; o4.y = (bf16)v.y; o4.z = (bf16)v.z; o4.w = (bf16)v.w;
    ((bf16x4*)xb)[i] = o4;
    return;
  }
  // ---- 64x64 transpose-convert, float4 loads, bf16x8 stores ----
  __shared__ float tile[64][65];  // stride 65: 2-way bank alias (free)
  const float* src;
  int k0, n0, col, srcN, dstK;
  bf16* dst;
  if (blk < 15872) {
    const int idx = blk - 13312;           // 40 x 64
    k0 = (idx % 40) * 64; n0 = (idx / 40) * 64;
    dstK = 2560; dst = wqkv_t;
    if (n0 < 2048)      { src = wq; col = n0;        srcN = 2048; }
    else if (n0 < 3072) { src = wk; col = n0 - 2048; srcN = 1024; }
    else                { src = wv; col = n0 - 3072; srcN = 1024; }
  } else {
    const int idx = blk - 15872;           // 32 x 40
    k0 = (idx & 31) * 64; n0 = (idx >> 5) * 64;
    dstK = 2048; dst = wo_t; src = wo; col = n0; srcN = 2560;
  }
  {
    const int rf = tid >> 4, c4 = (tid & 15) * 4;
#pragma unroll
    for (int i = 0; i < 4; ++i) {  // 16 rows per iter, 256B contiguous per row
      const int r = i * 16 + rf;
      const float4 v = *(const float4*)(src + (long)(k0 + r) * srcN + col + c4);
      tile[r][c4] = v.x; tile[r][c4 + 1] = v.y;
      tile[r][c4 + 2] = v.z; tile[r][c4 + 3] = v.w;
    }
  }
  __syncthreads();
  {
    const int nf = tid >> 3, kc = (tid & 7) * 8;
#pragma unroll
    for (int i = 0; i < 2; ++i) {  // 32 dst rows per iter, 128B/row
      const int nn = i * 32 + nf;
      bf16x8 o8;
#pragma unroll
      for (int j = 0; j < 8; ++j) o8[j] = (bf16)tile[kc + j][nn];
      *(bf16x8*)(dst + (long)(n0 + nn) * dstK + k0 + kc) = o8;
    }
  }
}

// ---------------- V path: qkv slice -> vout (f32 scatter) + vt bf16 [d][s] ----
__global__ __launch_bounds__(256) void v_trans_kernel(const bf16* __restrict__ qkv,
                                                      const int* __restrict__ p_ci,
                                                      float* __restrict__ vout,
                                                      bf16* __restrict__ vt) {
  __shared__ float tile[32][33];
  const int s0 = blockIdx.x * 32, d0 = blockIdx.y * 32, bk = blockIdx.z;
  const int b = bk >> 2, kvh = bk & 3;
  const int ci = *p_ci;
  const int tx = threadIdx.x, ty = threadIdx.y;
#pragma unroll
  for (int i = 0; i < 4; ++i) {
    const int s = s0 + ty + i * 8;
    const float val =
        (float)qkv[(long)(b * 1024 + s) * 4096 + (12 + kvh) * 256 + d0 + tx];
    tile[ty + i * 8][tx] = val;
    vout[((long)bk * 4096 + ci + s) * 256 + d0 + tx] = val;
  }
  __syncthreads();
  bf16* dstb = vt + ((long)bk * 256 + d0) * 1024 + s0;
#pragma unroll
  for (int i = 0; i < 4; ++i)
    dstb[(long)(ty + i * 8) * 1024 + tx] = (bf16)tile[tx][ty + i * 8];
}

// ---------------- bf16 MFMA GEMM: C(MxN) = A(MxK) * BT(NxK)^T ----------------
// BK=32, explicit LDS double-buffer; GLL prefetch of tile k+1 issued right
// after the barrier, drains during compute of tile k (one barrier per iter).
template <int BM, int BN, int K, int N, typename OutT>
__global__ __launch_bounds__(256) void gemm_kernel(const bf16* __restrict__ A,
                                                   const bf16* __restrict__ BT,
                                                   OutT* __restrict__ C) {
  __shared__ bf16 As[2 * BM * 32];
  __shared__ bf16 Bs[2 * BN * 32];
  const int bm = blockIdx.x, bn = blockIdx.y;
  const int tid = threadIdx.x;
  const int wave = tid >> 6, lane = tid & 63;
  const int quad = lane >> 4, l16 = lane & 15;
  constexpr int WM = BM / 2, WN = BN / 2;
  constexpr int MI = WM / 16, NI = WN / 16;
  const int wm = (wave & 1) * WM, wn = (wave >> 1) * WN;
  f32x4 acc[MI][NI] = {};
  const int srow = tid >> 2;
  const int sslot = tid & 3;
  const bf16* Ag = A + (long)(bm * BM) * K;
  const bf16* Bg = BT + (long)(bn * BN) * K;
  auto stage = [&](int buf, int k0) {
#pragma unroll
    for (int i = 0; i < BM / 64; ++i) {
      const int r = i * 64 + srow;
      const int cc = (sslot - (r >> 1)) & 3;
      GLL(As + buf * BM * 32 + (i * 256 + wave * 64) * 8,
          Ag + (long)r * K + k0 + cc * 8);
    }
#pragma unroll
    for (int i = 0; i < BN / 64; ++i) {
      const int r = i * 64 + srow;
      const int cc = (sslot - (r >> 1)) & 3;
      GLL(Bs + buf * BN * 32 + (i * 256 + wave * 64) * 8,
          Bg + (long)r * K + k0 + cc * 8);
    }
  };
  stage(0, 0);
  int buf = 0;
  for (int k0 = 0; k0 < K; k0 += 32) {
    __syncthreads();  // drains vmcnt: buf ready; prev iter's ds_reads done
    if (k0 + 32 < K) stage(buf ^ 1, k0 + 32);  // overlaps compute below
    const bf16* Ab = As + buf * BM * 32;
    const bf16* Bb = Bs + buf * BN * 32;
    bf16x8 af[MI], bfr[NI];
#pragma unroll
    for (int mi = 0; mi < MI; ++mi) {
      const int r = wm + mi * 16 + l16;
      af[mi] = *(const bf16x8*)(Ab + r * 32 + (((quad + (r >> 1)) & 3) * 8));
    }
#pragma unroll
    for (int ni = 0; ni < NI; ++ni) {
      const int r = wn + ni * 16 + l16;
      bfr[ni] = *(const bf16x8*)(Bb + r * 32 + (((quad + (r >> 1)) & 3) * 8));
    }
#pragma unroll
    for (int mi = 0; mi < MI; ++mi)
#pragma unroll
      for (int ni = 0; ni < NI; ++ni)
        acc[mi][ni] = MFMA16(af[mi], bfr[ni], acc[mi][ni]);
    buf ^= 1;
  }
  const int crow = bm * BM + wm + quad * 4;
  const int ccol = bn * BN + wn + l16;
#pragma unroll
  for (int mi = 0; mi < MI; ++mi)
#pragma unroll
    for (int ni = 0; ni < NI; ++ni)
#pragma unroll
      for (int r = 0; r < 4; ++r)
        C[(long)(crow + mi * 16 + r) * N + ccol + ni * 16] = (OutT)acc[mi][ni][r];
}

// ---------------- RMSNorm + RoPE (q,k only; fast HW sin/cos) ----------------
__global__ __launch_bounds__(256) void normrope_kernel(
    const bf16* __restrict__ qkv, const float* __restrict__ qw,
    const float* __restrict__ kw, const int* __restrict__ p_pos,
    const int* __restrict__ p_ci, float* __restrict__ kout,
    bf16* __restrict__ q_bf, bf16* __restrict__ k_bf) {
  const int bt = blockIdx.x, slot = blockIdx.y;  // slot 0..7 q, 8..11 k
  const int t = bt & 1023, b = bt >> 10;
  const int d = threadIdx.x;
  const float val = (float)qkv[(long)bt * 4096 + slot * 256 + d];
  __shared__ float red[4];
  __shared__ float rowbuf[256];
  float ss = val * val;
#pragma unroll
  for (int i = 1; i < 64; i <<= 1) ss += __shfl_xor(ss, i);
  if ((d & 63) == 0) red[d >> 6] = ss;
  __syncthreads();
  const float tot = red[0] + red[1] + red[2] + red[3];
  const float rstd = rsqrtf(tot * (1.0f / 256.0f) + 1e-6f);
  const bool isq = slot < 8;
  const float wv = isq ? qw[d] : kw[d];
  const float nv = val * rstd * (1.0f + wv);
  rowbuf[d] = nv;
  __syncthreads();
  const int e = d & 127;
  const float inv_freq = exp2f((float)e * -0.10381025296522976f);
  const float ang = (float)(*p_pos + t) * inv_freq;
  // v_sin/v_cos take REVOLUTIONS; fract reduction. err ~2e-4 << bf16 eps.
  float rev = ang * 0.15915494309189535f;
  rev = rev - floorf(rev);
  const float sn = __builtin_amdgcn_sinf(rev);
  const float cs = __builtin_amdgcn_cosf(rev);
  float outv;
  if (d < 128) outv = nv * cs - rowbuf[d + 128] * sn;
  else         outv = nv * cs + rowbuf[d - 128] * sn;
  if (isq) {
    q_bf[((long)(b * 8 + slot) * 1024 + t) * 256 + d] = (bf16)outv;
  } else {
    const int kh = slot - 8;
    const int ci = *p_ci;
    kout[((long)(b * 4 + kh) * 4096 + ci + t) * 256 + d] = outv;
    k_bf[((long)(b * 4 + kh) * 1024 + t) * 256 + d] = (bf16)outv;
  }
}

// ---------------- flash attention over the T new tokens (all valid, no mask) ----
__global__ __launch_bounds__(256) void attn_kernel(const bf16* __restrict__ q_bf,
                                                   const bf16* __restrict__ k_bf,
                                                   const bf16* __restrict__ vt_bf,
                                                   bf16* __restrict__ attn) {
  __shared__ bf16 Ks[64 * 256];   // [s][d], chunk-swizzled
  __shared__ bf16 Vs[256 * 64];   // [d][s], chunk-swizzled
  __shared__ bf16 Ps[64 * 72];    // [t][s], +8 pad (VALU-written)
  const int qt = blockIdx.x, h = blockIdx.y, b = blockIdx.z;
  const int kvh = h >> 1;
  const int tid = threadIdx.x;
  const int wave = tid >> 6, lane = tid & 63, quad = lane >> 4, l16 = lane & 15;
  bf16x8 qf[8];
  const bf16* qg =
      q_bf + ((long)(b * 8 + h) * 1024 + qt * 64 + wave * 16 + l16) * 256 + quad * 8;
#pragma unroll
  for (int i = 0; i < 8; ++i) qf[i] = *(const bf16x8*)(qg + i * 32);
  f32x4 o[16] = {};
  float m_r[4] = {-1e30f, -1e30f, -1e30f, -1e30f};
  float l_r[4] = {0.f, 0.f, 0.f, 0.f};
  const float sfac = 0.0625f * 1.44269504088896f;  // SCALE * log2(e)
  const bf16* kgb = k_bf + (long)(b * 4 + kvh) * 1024 * 256;
  const bf16* vgb = vt_bf + (long)(b * 4 + kvh) * 256 * 1024;
  const int krow = tid >> 5, kccp = tid & 31;
  const int kcc = kccp ^ (krow & 7);
  const int vrow0 = tid >> 3, vccp = tid & 7;
  for (int st = 0; st < 16; ++st) {
    __syncthreads();  // previous iter's ds_reads done
#pragma unroll
    for (int i = 0; i < 8; ++i) {  // K tile 64x256
      GLL(Ks + (i * 256 + wave * 64) * 8,
          kgb + (long)(st * 64 + krow + i * 8) * 256 + kcc * 8);
    }
#pragma unroll
    for (int i = 0; i < 8; ++i) {  // V^T tile 256x64
      const int vr = vrow0 + i * 32;
      GLL(Vs + (i * 256 + wave * 64) * 8,
          vgb + (long)vr * 1024 + st * 64 + (vccp ^ (vr & 7)) * 8);
    }
    __syncthreads();  // drains vmcnt -> tiles visible
    f32x4 sacc[4] = {};
#pragma unroll
    for (int kk = 0; kk < 8; ++kk) {
#pragma unroll
      for (int ni = 0; ni < 4; ++ni) {
        const int r = ni * 16 + l16;
        bf16x8 kf = *(const bf16x8*)(Ks + r * 256 + (((kk * 4 + quad) ^ (r & 7)) * 8));
        sacc[ni] = MFMA16(qf[kk], kf, sacc[ni]);
      }
    }
    float alpha_r[4];
#pragma unroll
    for (int r = 0; r < 4; ++r) {
      float s0 = sacc[0][r] * sfac, s1 = sacc[1][r] * sfac;
      float s2 = sacc[2][r] * sfac, s3 = sacc[3][r] * sfac;
      float mx = fmaxf(fmaxf(s0, s1), fmaxf(s2, s3));
#pragma unroll
      for (int dd = 1; dd < 16; dd <<= 1) mx = fmaxf(mx, __shfl_xor(mx, dd));
      float mnew = fmaxf(m_r[r], mx);
      float al = exp2f(m_r[r] - mnew);
      m_r[r] = mnew;
      alpha_r[r] = al;
      float p0 = exp2f(s0 - mnew), p1 = exp2f(s1 - mnew);
      float p2 = exp2f(s2 - mnew), p3 = exp2f(s3 - mnew);
      float rs = p0 + p1 + p2 + p3;
#pragma unroll
      for (int dd = 1; dd < 16; dd <<= 1) rs += __shfl_xor(rs, dd);
      l_r[r] = l_r[r] * al + rs;
      const int prow = (wave * 16 + quad * 4 + r) * 72;
      Ps[prow + l16] = (bf16)p0;
      Ps[prow + 16 + l16] = (bf16)p1;
      Ps[prow + 32 + l16] = (bf16)p2;
      Ps[prow + 48 + l16] = (bf16)p3;
    }
#pragma unroll
    for (int n2 = 0; n2 < 16; ++n2) {
      f32x4 tv = o[n2];
      tv.x *= alpha_r[0]; tv.y *= alpha_r[1]; tv.z *= alpha_r[2]; tv.w *= alpha_r[3];
      o[n2] = tv;
    }
    __syncthreads();  // P visible
    bf16x8 pf0 = *(const bf16x8*)(Ps + (wave * 16 + l16) * 72 + quad * 8);
    bf16x8 pf1 = *(const bf16x8*)(Ps + (wave * 16 + l16) * 72 + 32 + quad * 8);
#pragma unroll
    for (int n2 = 0; n2 < 16; ++n2) {
      const int r = n2 * 16 + l16;
      bf16x8 vf0 = *(const bf16x8*)(Vs + r * 64 + ((quad ^ (r & 7)) * 8));
      o[n2] = MFMA16(pf0, vf0, o[n2]);
      bf16x8 vf1 = *(const bf16x8*)(Vs + r * 64 + (((4 + quad) ^ (r & 7)) * 8));
      o[n2] = MFMA16(pf1, vf1, o[n2]);
    }
  }
  float inv_l[4];
#pragma unroll
  for (int r = 0; r < 4; ++r) inv_l[r] = 1.0f / l_r[r];
  bf16* og = attn + ((long)(b * 1024 + qt * 64 + wave * 16 + quad * 4)) * 2048 +
             h * 256 + l16;
#pragma unroll
  for (int n2 = 0; n2 < 16; ++n2)
#pragma unroll
    for (int r = 0; r < 4; ++r)
      og[(long)r * 2048 + n2 * 16] = (bf16)(o[n2][r] * inv_l[r]);
}

extern "C" void kernel_launch(void* const* d_in, const int* in_sizes, int n_in,
                              void* d_out, int out_size, void* d_ws, size_t ws_size,
                              hipStream_t stream) {
  const float* x = (const float*)d_in[0];
  const float* k_cache = (const float*)d_in[1];
  const float* v_cache = (const float*)d_in[2];
  const float* wq = (const float*)d_in[3];
  const float* wk = (const float*)d_in[4];
  const float* wv = (const float*)d_in[5];
  const float* wo = (const float*)d_in[6];
  const float* qnw = (const float*)d_in[7];
  const float* knw = (const float*)d_in[8];
  const int* p_pos = (const int*)d_in[9];
  const int* p_ci = (const int*)d_in[10];

  float* out0 = (float*)d_out;                    // (2,1024,2560)
  float* kout = out0 + (long)2 * 1024 * 2560;     // (2,4,4096,256)
  float* vout = kout + (long)2 * 4 * 4096 * 256;  // (2,4,4096,256)

  char* w = (char*)d_ws;
  bf16* x_bf = (bf16*)(w);                  // 2048x2560 bf16        10,485,760 B
  bf16* wqkv_t = (bf16*)(w + 10485760);     // 4096x2560 bf16        20,971,520 B
  bf16* wo_t = (bf16*)(w + 31457280);       // 2560x2048 bf16        10,485,760 B
  bf16* qkv = (bf16*)(w + 41943040);        // 2048x4096 bf16        16,777,216 B
  bf16* q_bf = (bf16*)(w + 58720256);       // (2,8,1024,256) bf16    8,388,608 B
  bf16* k_bf = (bf16*)(w + 67108864);       // (2,4,1024,256) bf16    4,194,304 B
  bf16* vt_bf = (bf16*)(w + 71303168);      // (2,4,256,1024) bf16    4,194,304 B
  bf16* attn_b = (bf16*)(w + 75497472);     // 2048x2048 bf16         8,388,608 B

  // 1. fused prologue (cache copy + x cvt + vectorized weight transposes)
  prep_kernel<<<17152, 256, 0, stream>>>(k_cache, v_cache, kout, vout, p_ci, x,
                                         x_bf, wq, wk, wv, wqkv_t, wo, wo_t);

  // 2. fused QKV projection — 128x128 dbuf tiles, bf16 output
  gemm_kernel<128, 128, 2560, 4096, bf16>
      <<<dim3(16, 32), 256, 0, stream>>>(x_bf, wqkv_t, qkv);

  // 3a. V path straight from qkv: vout f32 scatter + vt bf16 transpose
  dim3 tb(32, 8);
  v_trans_kernel<<<dim3(32, 8, 8), tb, 0, stream>>>(qkv, p_ci, vout, vt_bf);

  // 3b. rmsnorm + rope for q,k (fast HW sin/cos)
  normrope_kernel<<<dim3(2048, 12), 256, 0, stream>>>(qkv, qnw, knw, p_pos, p_ci,
                                                      kout, q_bf, k_bf);

  // 4. attention
  attn_kernel<<<dim3(16, 8, 2), 256, 0, stream>>>(q_bf, k_bf, vt_bf, attn_b);

  // 5. output projection — 64x128 dbuf tiles (grid 32x20 = 640 blocks), f32 out
  gemm_kernel<64, 128, 2048, 2560, float>
      <<<dim3(32, 20), 256, 0, stream>>>(attn_b, wo_t, out0);
}